// Round 11
// baseline (40.832 us; speedup 1.0000x reference)
//
#include <hip/hip_runtime.h>
#include <math.h>

#define Bdim 64
#define Tdim 512
#define Sdim 400
#define Hdim 768
#define Ldim 9
#define PSTRIDE 12  // padded proj row stride

#define PROJ_BLOCKS 2048
#define ROWS_PER_BLK 16  // 2048 * 16 = 32768 = B*T rows, ALL projected

// ---------------------------------------------------------------------------
// DPP 64-lane sum (row_shr 1/2/4/8 + row_bcast 15/31), result in lane 63.
// ---------------------------------------------------------------------------
template <int CTRL>
__device__ __forceinline__ float dpp_add(float x) {
  int y = __builtin_amdgcn_update_dpp(0, __float_as_int(x), CTRL, 0xF, 0xF, false);
  return x + __int_as_float(y);
}
__device__ __forceinline__ float wave_sum63(float x) {
  x = dpp_add<0x111>(x);
  x = dpp_add<0x112>(x);
  x = dpp_add<0x114>(x);
  x = dpp_add<0x118>(x);
  x = dpp_add<0x142>(x);
  x = dpp_add<0x143>(x);
  return x;  // lane 63 = sum of all 64 lanes
}

// ---------------------------------------------------------------------------
// Kernel 1: streaming projection of ALL rows, CHUNK-split (zero redundancy).
// Block = 192 threads = 3 waves. Wave w loads only chunk w (256 floats,
// 1 float4/lane) of each of the block's 16 rows -- each byte of enc is
// load-issued exactly once (R9's L-split issued every row 3x). Each wave
// computes partial dots for ALL 9 logits with a 36-float W fragment (the
// register-resident size proven since R6; R5's VGPR=80 showed 108-float
// fragments silently rematerialize). Partials -> LDS; one barrier; 144
// threads combine and write proj coalesced.
// Unconditional straight-line pipeline (R10: per-row predication broke
// scheduling and regressed). Depth-4 row buffers, fully unrolled.
// Block 0 zeroes the loss accumulators (ws is not re-poisoned).
// ---------------------------------------------------------------------------
__global__ __launch_bounds__(192, 4) void proj_kernel(
    const float* __restrict__ enc, const float* __restrict__ W,
    float* __restrict__ proj, float* __restrict__ accum,
    unsigned* __restrict__ counter) {
  int tid = threadIdx.x;
  int lane = tid & 63;
  int w = tid >> 6;  // chunk id 0..2
  int base = blockIdx.x * ROWS_PER_BLK;

  if (blockIdx.x == 0) {
    if (tid < 2) accum[tid] = 0.0f;
    if (tid == 2) *counter = 0u;
  }

  __shared__ float part[ROWS_PER_BLK][3][PSTRIDE];  // [row][chunk][logit]

  // per-lane W fragment: h = w*256 + 4*lane + j (j<4), all 9 logits
  float wf[4][Ldim];
#pragma unroll
  for (int j = 0; j < 4; ++j) {
    int h = w * 256 + 4 * lane + j;
#pragma unroll
    for (int c = 0; c < Ldim; ++c) wf[j][c] = W[(size_t)h * Ldim + c];
  }

  // wave w's float4 for row r sits at enc4[r*192 + w*64 + lane]
  const float4* encf4 = (const float4*)enc;
  const float4* src = encf4 + (size_t)base * (Hdim / 4) + w * 64 + lane;

  float4 buf0, buf1, buf2, buf3;
#define LDR(BUF, I) BUF = src[(size_t)(I) * (Hdim / 4)];
#define PRC(BUF, I)                                                        \
  {                                                                        \
    float dd[Ldim];                                                        \
    _Pragma("unroll") for (int c = 0; c < Ldim; ++c) {                     \
      dd[c] = BUF.x * wf[0][c] + BUF.y * wf[1][c] +                        \
              BUF.z * wf[2][c] + BUF.w * wf[3][c];                         \
      dd[c] = wave_sum63(dd[c]);                                           \
    }                                                                      \
    if (lane == 63) {                                                      \
      _Pragma("unroll") for (int c = 0; c < Ldim; ++c)                     \
        part[I][w][c] = dd[c];                                             \
    }                                                                      \
  }

  LDR(buf0, 0) LDR(buf1, 1) LDR(buf2, 2) LDR(buf3, 3)
  PRC(buf0, 0)  LDR(buf0, 4)
  PRC(buf1, 1)  LDR(buf1, 5)
  PRC(buf2, 2)  LDR(buf2, 6)
  PRC(buf3, 3)  LDR(buf3, 7)
  PRC(buf0, 4)  LDR(buf0, 8)
  PRC(buf1, 5)  LDR(buf1, 9)
  PRC(buf2, 6)  LDR(buf2, 10)
  PRC(buf3, 7)  LDR(buf3, 11)
  PRC(buf0, 8)  LDR(buf0, 12)
  PRC(buf1, 9)  LDR(buf1, 13)
  PRC(buf2, 10) LDR(buf2, 14)
  PRC(buf3, 11) LDR(buf3, 15)
  PRC(buf0, 12)
  PRC(buf1, 13)
  PRC(buf2, 14)
  PRC(buf3, 15)
#undef LDR
#undef PRC

  __syncthreads();
  // combine: thread t < 144 handles (row, logit); coalesced proj write
  if (tid < ROWS_PER_BLK * Ldim) {
    int row = tid / Ldim;
    int l = tid - row * Ldim;
    float v = part[row][0][l] + part[row][1][l] + part[row][2][l];
    proj[(size_t)(base + row) * PSTRIDE + l] = v;
  }
}

// ---------------------------------------------------------------------------
// Kernel 2 (R9 verbatim): one block per batch row (512 threads, 8 waves).
//  phase A: both scans in LDS; phase B: 400 words: mean of token proj rows,
//  +bias, argmax -> out, NLL partial; phase C: block reduce, 64 block
//  atomics, last block finalizes loss.
// ---------------------------------------------------------------------------
__global__ __launch_bounds__(Tdim) void rowword_kernel(
    const float* __restrict__ proj, const float* __restrict__ bias,
    const int* __restrict__ attn, const int* __restrict__ ids_lens,
    const int* __restrict__ label_ids, float* __restrict__ out,
    float* __restrict__ accum, unsigned* __restrict__ counter) {
  int b = blockIdx.x;
  int tid = threadIdx.x;
  int lane = tid & 63, wid = tid >> 6;
  __shared__ int p2t[Tdim];
  __shared__ int wst[Sdim];
  __shared__ int wsum[8];
  __shared__ int totsm;
  __shared__ float ssm[8], csm[8];

  // ---- scan 1: attention mask -> p2t (LDS), nvalid ----
  int m = attn[b * Tdim + tid];
  int x = m;
#pragma unroll
  for (int off = 1; off < 64; off <<= 1) {
    int v = __shfl_up(x, off, 64);
    if (lane >= off) x += v;
  }
  if (lane == 63) wsum[wid] = x;
  __syncthreads();
  if (tid < 8) {
    int s = wsum[tid], y = s;
#pragma unroll
    for (int off = 1; off < 8; off <<= 1) {
      int v = __shfl_up(y, off, 64);
      if (tid >= off) y += v;
    }
    wsum[tid] = y - s;
    if (tid == 7) totsm = y;
  }
  __syncthreads();
  x += wsum[wid];
  if (m) p2t[x - 1] = tid;  // q-th valid token -> physical position
  int nv_local = totsm;
  __syncthreads();

  // ---- scan 2: ids_lens -> wstart (LDS) ----
  int len = (tid < Sdim) ? ids_lens[b * Sdim + tid] : 0;
  int x2 = len;
#pragma unroll
  for (int off = 1; off < 64; off <<= 1) {
    int v = __shfl_up(x2, off, 64);
    if (lane >= off) x2 += v;
  }
  if (lane == 63) wsum[wid] = x2;
  __syncthreads();
  if (tid < 8) {
    int s = wsum[tid], y = s;
#pragma unroll
    for (int off = 1; off < 8; off <<= 1) {
      int v = __shfl_up(y, off, 64);
      if (tid >= off) y += v;
    }
    wsum[tid] = y - s;
  }
  __syncthreads();
  x2 += wsum[wid];
  if (tid < Sdim) wst[tid] = x2 - len;
  __syncthreads();

  // ---- phase B: words ----
  float nll = 0.0f, cnt = 0.0f;
  if (tid < Sdim) {
    int bs = b * Sdim + tid;
    float sum[Ldim];
#pragma unroll
    for (int l = 0; l < Ldim; ++l) sum[l] = 0.0f;
    if (len > 0) {
      int start = wst[tid];
      for (int j = 0; j < len; ++j) {
        int q = start + j;
        if (q >= nv_local) break;
        const float* pr = proj + ((size_t)(b << 9) + p2t[q]) * PSTRIDE;
        const float4* pr4 = (const float4*)pr;
        float4 r0 = pr4[0], r1 = pr4[1];
        float r8 = pr[8];
        sum[0] += r0.x; sum[1] += r0.y; sum[2] += r0.z; sum[3] += r0.w;
        sum[4] += r1.x; sum[5] += r1.y; sum[6] += r1.z; sum[7] += r1.w;
        sum[8] += r8;
      }
    }
    float inv = (len > 0) ? 1.0f / (float)len : 0.0f;
    float lg[Ldim];
#pragma unroll
    for (int l = 0; l < Ldim; ++l) lg[l] = sum[l] * inv + bias[l];

    int amax = 0;
    float mx = lg[0];
#pragma unroll
    for (int l = 1; l < Ldim; ++l)
      if (lg[l] > mx) { mx = lg[l]; amax = l; }
    out[1 + bs] = (float)amax;

    if (len > 0) {
      float se = 0.0f;
#pragma unroll
      for (int l = 0; l < Ldim; ++l) se += expf(lg[l] - mx);
      float lse = mx + logf(se);
      int lab = label_ids[bs];
      float ll = lg[0];
#pragma unroll
      for (int l = 1; l < Ldim; ++l) ll = (lab == l) ? lg[l] : ll;
      nll = lse - ll;
      cnt = 1.0f;
    }
  }

  // ---- phase C: block reduce + finalize ----
#pragma unroll
  for (int off = 32; off > 0; off >>= 1) {
    nll += __shfl_down(nll, off, 64);
    cnt += __shfl_down(cnt, off, 64);
  }
  if (lane == 0) { ssm[wid] = nll; csm[wid] = cnt; }
  __syncthreads();
  if (tid == 0) {
    float S = 0.f, C = 0.f;
#pragma unroll
    for (int k = 0; k < 8; ++k) { S += ssm[k]; C += csm[k]; }
    atomicAdd(&accum[0], S);
    atomicAdd(&accum[1], C);
    __threadfence();
    unsigned prev = atomicAdd(counter, 1u);
    if (prev == gridDim.x - 1) {
      __threadfence();
      float Sf = atomicAdd(&accum[0], 0.0f);
      float Cf = atomicAdd(&accum[1], 0.0f);
      out[0] = Sf / Cf;
    }
  }
}

extern "C" void kernel_launch(void* const* d_in, const int* in_sizes, int n_in,
                              void* d_out, int out_size, void* d_ws, size_t ws_size,
                              hipStream_t stream) {
  const float* enc     = (const float*)d_in[0];  // [B,T,H] f32
  const float* W       = (const float*)d_in[1];  // [H,L]   f32
  const float* bias    = (const float*)d_in[2];  // [L]     f32
  const int* attn      = (const int*)d_in[3];    // [B,T]   i32
  const int* ids_lens  = (const int*)d_in[4];    // [B,S]   i32
  const int* label_ids = (const int*)d_in[5];    // [B,S]   i32
  // d_in[6] label_mask is recomputed from ids_lens>0

  float* out = (float*)d_out;  // [1 + B*S]: loss, then argmax as float

  char* ws = (char*)d_ws;
  size_t off0 = 0;
  float* accum      = (float*)(ws + off0);    off0 += 128;
  unsigned* counter = (unsigned*)(ws + off0); off0 += 128;
  float* proj       = (float*)(ws + off0);    off0 += (size_t)Bdim * Tdim * PSTRIDE * sizeof(float);

  proj_kernel<<<PROJ_BLOCKS, 192, 0, stream>>>(enc, W, proj, accum, counter);
  rowword_kernel<<<Bdim, Tdim, 0, stream>>>(proj, bias, attn, ids_lens,
                                            label_ids, out, accum, counter);
}

// Round 12
// 35.070 us; speedup vs baseline: 1.1643x; 1.1643x over previous
//
#include <hip/hip_runtime.h>
#include <math.h>

#define Bdim 64
#define Tdim 512
#define Sdim 400
#define Hdim 768
#define Ldim 9
#define PSTRIDE 12  // padded proj row stride

#define PROJ_BLOCKS 2048
#define ROWS_PER_BLK 16  // 2048 * 16 = 32768 = B*T rows, ALL projected

typedef float v2f __attribute__((ext_vector_type(2)));

// ---------------------------------------------------------------------------
// DPP add helper (old=0: out-of-row sources contribute 0). Pure VALU.
// ---------------------------------------------------------------------------
template <int CTRL>
__device__ __forceinline__ float dpp_add(float x) {
  int y = __builtin_amdgcn_update_dpp(0, __float_as_int(x), CTRL, 0xF, 0xF, false);
  return x + __int_as_float(y);
}
// 32-lane segmented sum: after row_shr 1/2/4/8 + row_bcast:15,
// lane31 = sum(lanes 0..31), lane63 = sum(lanes 32..63).
__device__ __forceinline__ float rsum32(float x) {
  x = dpp_add<0x111>(x);  // row_shr:1
  x = dpp_add<0x112>(x);  // row_shr:2
  x = dpp_add<0x114>(x);  // row_shr:4
  x = dpp_add<0x118>(x);  // row_shr:8
  x = dpp_add<0x142>(x);  // row_bcast:15
  return x;
}

// ---------------------------------------------------------------------------
// Kernel 1: streaming projection of ALL rows. R9 structure (best measured),
// with the two VALU cuts R11 motivated:
//  - packed fp32 FMA (v_pk_fma_f32 via elementwise_fma on float2): halves FMA
//  - 2 rows/wave (lanes 0-31 row 2i, lanes 32-63 row 2i+1), 32-lane DPP
//    reduce: 5 steps amortized over 2 rows (45 insts/row vs R9's 108)
// W fragment = 72 floats/lane (36 v2f), register-resident; launch_bounds
// min-waves=2 allows 256 VGPR so the compiler won't rematerialize (R5 tell).
// Loads for pair i+2 issue between FMA and reduce (waitcnt cover).
// Block 0 zeroes the loss accumulators (ws is not re-poisoned).
// ---------------------------------------------------------------------------
__global__ __launch_bounds__(192, 2) void proj_kernel(
    const float* __restrict__ enc, const float* __restrict__ W,
    float* __restrict__ proj, float* __restrict__ accum,
    unsigned* __restrict__ counter) {
  int tid = threadIdx.x;
  int lane = tid & 63;
  int w = tid >> 6;       // 0..2
  int l0 = w * 3;         // logit slice {l0, l0+1, l0+2}
  int lr = lane & 31;     // lane within row
  int half = lane >> 5;   // 0: even row of pair, 1: odd row
  int base = blockIdx.x * ROWS_PER_BLK;

  if (blockIdx.x == 0) {
    if (tid < 2) accum[tid] = 0.0f;
    if (tid == 2) *counter = 0u;
  }

  // W fragment: h(k,j) = lr*4 + k*128 + j (k<6, j<4), packed as j-pairs
  v2f wf[6][2][3];
#pragma unroll
  for (int k = 0; k < 6; ++k)
#pragma unroll
    for (int p = 0; p < 2; ++p)
#pragma unroll
      for (int c = 0; c < 3; ++c) {
        int h = lr * 4 + k * 128 + 2 * p;
        wf[k][p][c] = (v2f){W[(size_t)h * Ldim + l0 + c],
                            W[(size_t)(h + 1) * Ldim + l0 + c]};
      }

  const float4* __restrict__ encf4 = (const float4*)enc;

  float4 A0, A1, A2, A3, A4, A5;
  float4 B0, B1, B2, B3, B4, B5;

#define LD(S, IT)                                                             \
  {                                                                           \
    const float4* r_ =                                                        \
        encf4 + (size_t)(base + 2 * (IT) + half) * (Hdim / 4) + lr;           \
    S##0 = r_[0];   S##1 = r_[32];  S##2 = r_[64];                            \
    S##3 = r_[96];  S##4 = r_[128]; S##5 = r_[160];                           \
  }

#define FMAK(X, K)                                                            \
  {                                                                           \
    v2f p0 = {X.x, X.y}, p1 = {X.z, X.w};                                     \
    ac0 = __builtin_elementwise_fma(p0, wf[K][0][0], ac0);                    \
    ac1 = __builtin_elementwise_fma(p0, wf[K][0][1], ac1);                    \
    ac2 = __builtin_elementwise_fma(p0, wf[K][0][2], ac2);                    \
    ac0 = __builtin_elementwise_fma(p1, wf[K][1][0], ac0);                    \
    ac1 = __builtin_elementwise_fma(p1, wf[K][1][1], ac1);                    \
    ac2 = __builtin_elementwise_fma(p1, wf[K][1][2], ac2);                    \
  }

#define STEP(S, IT, NXT)                                                      \
  {                                                                           \
    v2f ac0 = {0.f, 0.f}, ac1 = {0.f, 0.f}, ac2 = {0.f, 0.f};                 \
    FMAK(S##0, 0) FMAK(S##1, 1) FMAK(S##2, 2)                                 \
    FMAK(S##3, 3) FMAK(S##4, 4) FMAK(S##5, 5)                                 \
    if ((NXT) < ROWS_PER_BLK / 2) LD(S, NXT)                                  \
    float d0 = ac0.x + ac0.y;                                                 \
    float d1 = ac1.x + ac1.y;                                                 \
    float d2 = ac2.x + ac2.y;                                                 \
    d0 = rsum32(d0); d1 = rsum32(d1); d2 = rsum32(d2);                        \
    if ((lane & 31) == 31) {                                                  \
      float* dst = proj + (size_t)(base + 2 * (IT) + half) * PSTRIDE + l0;    \
      dst[0] = d0; dst[1] = d1; dst[2] = d2;                                  \
    }                                                                         \
  }

  LD(A, 0)
  LD(B, 1)
  STEP(A, 0, 2)
  STEP(B, 1, 3)
  STEP(A, 2, 4)
  STEP(B, 3, 5)
  STEP(A, 4, 6)
  STEP(B, 5, 7)
  STEP(A, 6, 8)
  STEP(B, 7, 9)
#undef LD
#undef FMAK
#undef STEP
}

// ---------------------------------------------------------------------------
// Kernel 2 (R9 verbatim): one block per batch row (512 threads, 8 waves).
//  phase A: both scans in LDS; phase B: 400 words: mean of token proj rows,
//  +bias, argmax -> out, NLL partial; phase C: block reduce, 64 block
//  atomics, last block finalizes loss.
// ---------------------------------------------------------------------------
__global__ __launch_bounds__(Tdim) void rowword_kernel(
    const float* __restrict__ proj, const float* __restrict__ bias,
    const int* __restrict__ attn, const int* __restrict__ ids_lens,
    const int* __restrict__ label_ids, float* __restrict__ out,
    float* __restrict__ accum, unsigned* __restrict__ counter) {
  int b = blockIdx.x;
  int tid = threadIdx.x;
  int lane = tid & 63, wid = tid >> 6;
  __shared__ int p2t[Tdim];
  __shared__ int wst[Sdim];
  __shared__ int wsum[8];
  __shared__ int totsm;
  __shared__ float ssm[8], csm[8];

  // ---- scan 1: attention mask -> p2t (LDS), nvalid ----
  int m = attn[b * Tdim + tid];
  int x = m;
#pragma unroll
  for (int off = 1; off < 64; off <<= 1) {
    int v = __shfl_up(x, off, 64);
    if (lane >= off) x += v;
  }
  if (lane == 63) wsum[wid] = x;
  __syncthreads();
  if (tid < 8) {
    int s = wsum[tid], y = s;
#pragma unroll
    for (int off = 1; off < 8; off <<= 1) {
      int v = __shfl_up(y, off, 64);
      if (tid >= off) y += v;
    }
    wsum[tid] = y - s;
    if (tid == 7) totsm = y;
  }
  __syncthreads();
  x += wsum[wid];
  if (m) p2t[x - 1] = tid;  // q-th valid token -> physical position
  int nv_local = totsm;
  __syncthreads();

  // ---- scan 2: ids_lens -> wstart (LDS) ----
  int len = (tid < Sdim) ? ids_lens[b * Sdim + tid] : 0;
  int x2 = len;
#pragma unroll
  for (int off = 1; off < 64; off <<= 1) {
    int v = __shfl_up(x2, off, 64);
    if (lane >= off) x2 += v;
  }
  if (lane == 63) wsum[wid] = x2;
  __syncthreads();
  if (tid < 8) {
    int s = wsum[tid], y = s;
#pragma unroll
    for (int off = 1; off < 8; off <<= 1) {
      int v = __shfl_up(y, off, 64);
      if (tid >= off) y += v;
    }
    wsum[tid] = y - s;
  }
  __syncthreads();
  x2 += wsum[wid];
  if (tid < Sdim) wst[tid] = x2 - len;
  __syncthreads();

  // ---- phase B: words ----
  float nll = 0.0f, cnt = 0.0f;
  if (tid < Sdim) {
    int bs = b * Sdim + tid;
    float sum[Ldim];
#pragma unroll
    for (int l = 0; l < Ldim; ++l) sum[l] = 0.0f;
    if (len > 0) {
      int start = wst[tid];
      for (int j = 0; j < len; ++j) {
        int q = start + j;
        if (q >= nv_local) break;
        const float* pr = proj + ((size_t)(b << 9) + p2t[q]) * PSTRIDE;
        const float4* pr4 = (const float4*)pr;
        float4 r0 = pr4[0], r1 = pr4[1];
        float r8 = pr[8];
        sum[0] += r0.x; sum[1] += r0.y; sum[2] += r0.z; sum[3] += r0.w;
        sum[4] += r1.x; sum[5] += r1.y; sum[6] += r1.z; sum[7] += r1.w;
        sum[8] += r8;
      }
    }
    float inv = (len > 0) ? 1.0f / (float)len : 0.0f;
    float lg[Ldim];
#pragma unroll
    for (int l = 0; l < Ldim; ++l) lg[l] = sum[l] * inv + bias[l];

    int amax = 0;
    float mx = lg[0];
#pragma unroll
    for (int l = 1; l < Ldim; ++l)
      if (lg[l] > mx) { mx = lg[l]; amax = l; }
    out[1 + bs] = (float)amax;

    if (len > 0) {
      float se = 0.0f;
#pragma unroll
      for (int l = 0; l < Ldim; ++l) se += expf(lg[l] - mx);
      float lse = mx + logf(se);
      int lab = label_ids[bs];
      float ll = lg[0];
#pragma unroll
      for (int l = 1; l < Ldim; ++l) ll = (lab == l) ? lg[l] : ll;
      nll = lse - ll;
      cnt = 1.0f;
    }
  }

  // ---- phase C: block reduce + finalize ----
#pragma unroll
  for (int off = 32; off > 0; off >>= 1) {
    nll += __shfl_down(nll, off, 64);
    cnt += __shfl_down(cnt, off, 64);
  }
  if (lane == 0) { ssm[wid] = nll; csm[wid] = cnt; }
  __syncthreads();
  if (tid == 0) {
    float S = 0.f, C = 0.f;
#pragma unroll
    for (int k = 0; k < 8; ++k) { S += ssm[k]; C += csm[k]; }
    atomicAdd(&accum[0], S);
    atomicAdd(&accum[1], C);
    __threadfence();
    unsigned prev = atomicAdd(counter, 1u);
    if (prev == gridDim.x - 1) {
      __threadfence();
      float Sf = atomicAdd(&accum[0], 0.0f);
      float Cf = atomicAdd(&accum[1], 0.0f);
      out[0] = Sf / Cf;
    }
  }
}

extern "C" void kernel_launch(void* const* d_in, const int* in_sizes, int n_in,
                              void* d_out, int out_size, void* d_ws, size_t ws_size,
                              hipStream_t stream) {
  const float* enc     = (const float*)d_in[0];  // [B,T,H] f32
  const float* W       = (const float*)d_in[1];  // [H,L]   f32
  const float* bias    = (const float*)d_in[2];  // [L]     f32
  const int* attn      = (const int*)d_in[3];    // [B,T]   i32
  const int* ids_lens  = (const int*)d_in[4];    // [B,S]   i32
  const int* label_ids = (const int*)d_in[5];    // [B,S]   i32
  // d_in[6] label_mask is recomputed from ids_lens>0

  float* out = (float*)d_out;  // [1 + B*S]: loss, then argmax as float

  char* ws = (char*)d_ws;
  size_t off0 = 0;
  float* accum      = (float*)(ws + off0);    off0 += 128;
  unsigned* counter = (unsigned*)(ws + off0); off0 += 128;
  float* proj       = (float*)(ws + off0);    off0 += (size_t)Bdim * Tdim * PSTRIDE * sizeof(float);

  proj_kernel<<<PROJ_BLOCKS, 192, 0, stream>>>(enc, W, proj, accum, counter);
  rowword_kernel<<<Bdim, Tdim, 0, stream>>>(proj, bias, attn, ids_lens,
                                            label_ids, out, accum, counter);
}

// Round 14
// 33.001 us; speedup vs baseline: 1.2373x; 1.0627x over previous
//
#include <hip/hip_runtime.h>
#include <math.h>

#define Bdim 64
#define Tdim 512
#define Sdim 400
#define Hdim 768
#define Ldim 9

#define QWIN 130        // tokens projected per block: 128 + 2 overlap (len<=3)
#define LPROJ_ROWS 132  // LDS tile rows (padded)

// ---------------------------------------------------------------------------
// DPP 64-lane sum (row_shr 1/2/4/8 + row_bcast 15/31), result in lane 63.
// ---------------------------------------------------------------------------
template <int CTRL>
__device__ __forceinline__ float dpp_add(float x) {
  int y = __builtin_amdgcn_update_dpp(0, __float_as_int(x), CTRL, 0xF, 0xF, false);
  return x + __int_as_float(y);
}
__device__ __forceinline__ float wave_sum63(float x) {
  x = dpp_add<0x111>(x);
  x = dpp_add<0x112>(x);
  x = dpp_add<0x114>(x);
  x = dpp_add<0x118>(x);
  x = dpp_add<0x142>(x);
  x = dpp_add<0x143>(x);
  return x;  // lane 63 = sum of all 64 lanes
}

// ---------------------------------------------------------------------------
// Fused kernel: 256 blocks = (batch row b, quarter part). 512 threads.
//  A: per-row scans in LDS (p2t, wstart, nvalid)
//  B: project tokens q in [part*128, min(part*128+QWIN, nvalid)) into an LDS
//     tile. Valid-only (-25 MB vs R9). Waves 0-5 in two groups of 3; R9's
//     proven per-wave structure: full-row float4 loads (L2 dedups the 3x
//     issue), 3 logits via 36-float register W fragment (R5: bigger
//     fragments silently rematerialize), DPP reduce, lane63 -> LDS.
//     Ping-pong depth-2 with compile-time buffer names (rule #20).
//  C: after one barrier, each word whose wstart-bucket == part: mean from
//     LDS tile, +bias, argmax -> out, NLL -> block partial (plain store).
// Words bucketed by wstart>>7: every word has exactly one owner; its tokens
// (len<=3, start<=511) lie inside the owner's QWIN window.
// ---------------------------------------------------------------------------
__global__ __launch_bounds__(512, 2) void fused_kernel(
    const float* __restrict__ enc, const float* __restrict__ W,
    const float* __restrict__ bias, const int* __restrict__ attn,
    const int* __restrict__ ids_lens, const int* __restrict__ label_ids,
    float* __restrict__ out, float2* __restrict__ partials) {
  int blk = blockIdx.x;
  int b = blk >> 2;
  int part = blk & 3;
  int q0 = part << 7;
  int tid = threadIdx.x;
  int lane = tid & 63, wid = tid >> 6;

  __shared__ int p2t[Tdim];
  __shared__ int wst[Sdim];
  __shared__ float lproj[LPROJ_ROWS][12];
  __shared__ int wsum[8];
  __shared__ int totsm;
  __shared__ float ssm[8], csm[8];

  // ================= phase A: scans =================
  int m = attn[b * Tdim + tid];
  int x = m;
#pragma unroll
  for (int off = 1; off < 64; off <<= 1) {
    int v = __shfl_up(x, off, 64);
    if (lane >= off) x += v;
  }
  if (lane == 63) wsum[wid] = x;
  __syncthreads();
  if (tid < 8) {
    int s = wsum[tid], y = s;
#pragma unroll
    for (int off = 1; off < 8; off <<= 1) {
      int v = __shfl_up(y, off, 64);
      if (tid >= off) y += v;
    }
    wsum[tid] = y - s;
    if (tid == 7) totsm = y;
  }
  __syncthreads();
  x += wsum[wid];
  if (m) p2t[x - 1] = tid;  // q-th valid token -> physical position
  int nv = totsm;
  __syncthreads();  // p2t written; wsum reusable

  int len = (tid < Sdim) ? ids_lens[b * Sdim + tid] : 0;
  int x2 = len;
#pragma unroll
  for (int off = 1; off < 64; off <<= 1) {
    int v = __shfl_up(x2, off, 64);
    if (lane >= off) x2 += v;
  }
  if (lane == 63) wsum[wid] = x2;
  __syncthreads();
  if (tid < 8) {
    int s = wsum[tid], y = s;
#pragma unroll
    for (int off = 1; off < 8; off <<= 1) {
      int v = __shfl_up(y, off, 64);
      if (tid >= off) y += v;
    }
    wsum[tid] = y - s;
  }
  __syncthreads();
  x2 += wsum[wid];
  if (tid < Sdim) wst[tid] = x2 - len;  // exclusive prefix
  __syncthreads();

  // ================= phase B: project this block's token window =================
  int lim = q0 + QWIN;
  if (lim > nv) lim = nv;
  if (wid < 6) {
    int g = (wid >= 3) ? 1 : 0;     // token parity group
    int l0 = (wid - 3 * g) * 3;     // logit slice {l0..l0+2}
    // tokens q = q0 + g + 2k, k = 0..tc-1
    int tc = lim - q0 - g;
    tc = (tc > 0) ? ((tc + 1) >> 1) : 0;

    if (tc > 0) {
      // 36-float register W fragment: h = 4*lane + 256*k + j
      float wf[3][4][3];
#pragma unroll
      for (int k = 0; k < 3; ++k)
#pragma unroll
        for (int j = 0; j < 4; ++j) {
          int h = 4 * lane + 256 * k + j;
#pragma unroll
          for (int c = 0; c < 3; ++c) wf[k][j][c] = W[(size_t)h * Ldim + l0 + c];
        }
      const float4* encb = (const float4*)enc + (size_t)(b << 9) * (Hdim / 4);

      float4 A0, A1, A2, B0, B1, B2;
#define LDK(V0, V1, V2, K)                                                 \
  {                                                                        \
    int t_ = p2t[q0 + g + 2 * (K)];                                        \
    const float4* r_ = encb + (size_t)t_ * (Hdim / 4);                     \
    V0 = r_[lane]; V1 = r_[lane + 64]; V2 = r_[lane + 128];                \
  }
#define PRK(V0, V1, V2, K)                                                 \
  {                                                                        \
    float dd[3];                                                           \
    _Pragma("unroll") for (int c = 0; c < 3; ++c) {                        \
      dd[c] = V0.x * wf[0][0][c] + V0.y * wf[0][1][c] +                    \
              V0.z * wf[0][2][c] + V0.w * wf[0][3][c] +                    \
              V1.x * wf[1][0][c] + V1.y * wf[1][1][c] +                    \
              V1.z * wf[1][2][c] + V1.w * wf[1][3][c] +                    \
              V2.x * wf[2][0][c] + V2.y * wf[2][1][c] +                    \
              V2.z * wf[2][2][c] + V2.w * wf[2][3][c];                     \
      dd[c] = wave_sum63(dd[c]);                                           \
    }                                                                      \
    if (lane == 63) {                                                      \
      int row_ = g + 2 * (K);                                              \
      lproj[row_][l0 + 0] = dd[0];                                         \
      lproj[row_][l0 + 1] = dd[1];                                         \
      lproj[row_][l0 + 2] = dd[2];                                         \
    }                                                                      \
  }
      LDK(A0, A1, A2, 0)
      if (tc > 1) LDK(B0, B1, B2, 1)
      int k = 0;
      for (; k + 2 < tc; k += 2) {
        PRK(A0, A1, A2, k)
        LDK(A0, A1, A2, k + 2)
        PRK(B0, B1, B2, k + 1)
        if (k + 3 < tc) LDK(B0, B1, B2, k + 3)
      }
      PRK(A0, A1, A2, k)
      if (k + 1 < tc) PRK(B0, B1, B2, k + 1)
#undef LDK
#undef PRK
    }
  }
  __syncthreads();

  // ================= phase C: this block's words =================
  float nll = 0.0f, cnt = 0.0f;
  if (tid < Sdim) {
    int st = wst[tid];
    int stc = (st > 511) ? 511 : st;
    if ((stc >> 7) == part) {  // this block owns word tid
      int bs = b * Sdim + tid;
      float sum[Ldim];
#pragma unroll
      for (int l = 0; l < Ldim; ++l) sum[l] = 0.0f;
      if (len > 0) {
        for (int j = 0; j < len; ++j) {
          int q = st + j;
          if (q >= nv) break;
          const float* pr = lproj[q - q0];
#pragma unroll
          for (int l = 0; l < Ldim; ++l) sum[l] += pr[l];
        }
      }
      float inv = (len > 0) ? 1.0f / (float)len : 0.0f;
      float lg[Ldim];
#pragma unroll
      for (int l = 0; l < Ldim; ++l) lg[l] = sum[l] * inv + bias[l];

      int amax = 0;
      float mx = lg[0];
#pragma unroll
      for (int l = 1; l < Ldim; ++l)
        if (lg[l] > mx) { mx = lg[l]; amax = l; }
      out[1 + bs] = (float)amax;

      if (len > 0) {
        float se = 0.0f;
#pragma unroll
        for (int l = 0; l < Ldim; ++l) se += expf(lg[l] - mx);
        float lse = mx + logf(se);
        int lab = label_ids[bs];
        float ll = lg[0];
#pragma unroll
        for (int l = 1; l < Ldim; ++l) ll = (lab == l) ? lg[l] : ll;
        nll = lse - ll;
        cnt = 1.0f;
      }
    }
  }

#pragma unroll
  for (int off = 32; off > 0; off >>= 1) {
    nll += __shfl_down(nll, off, 64);
    cnt += __shfl_down(cnt, off, 64);
  }
  if (lane == 0) { ssm[wid] = nll; csm[wid] = cnt; }
  __syncthreads();
  if (tid == 0) {
    float S = 0.f, C = 0.f;
#pragma unroll
    for (int k = 0; k < 8; ++k) { S += ssm[k]; C += csm[k]; }
    float2 pc; pc.x = S; pc.y = C;
    partials[blk] = pc;  // plain store, no atomics
  }
}

// ---------------------------------------------------------------------------
// Finalize: 1 block, 256 threads: loss = sum(partials.x) / sum(partials.y)
// ---------------------------------------------------------------------------
__global__ __launch_bounds__(256) void final_kernel(
    const float2* __restrict__ partials, float* __restrict__ out) {
  int tid = threadIdx.x;
  float2 pc = partials[tid];  // 256 entries, one per thread
  float s = pc.x, c = pc.y;
#pragma unroll
  for (int off = 32; off > 0; off >>= 1) {
    s += __shfl_down(s, off, 64);
    c += __shfl_down(c, off, 64);
  }
  __shared__ float ss[4], cc[4];
  int wid = tid >> 6, lane = tid & 63;
  if (lane == 0) { ss[wid] = s; cc[wid] = c; }
  __syncthreads();
  if (tid == 0)
    out[0] = (ss[0] + ss[1] + ss[2] + ss[3]) / (cc[0] + cc[1] + cc[2] + cc[3]);
}

extern "C" void kernel_launch(void* const* d_in, const int* in_sizes, int n_in,
                              void* d_out, int out_size, void* d_ws, size_t ws_size,
                              hipStream_t stream) {
  const float* enc     = (const float*)d_in[0];  // [B,T,H] f32
  const float* W       = (const float*)d_in[1];  // [H,L]   f32
  const float* bias    = (const float*)d_in[2];  // [L]     f32
  const int* attn      = (const int*)d_in[3];    // [B,T]   i32
  const int* ids_lens  = (const int*)d_in[4];    // [B,S]   i32
  const int* label_ids = (const int*)d_in[5];    // [B,S]   i32
  // d_in[6] label_mask is recomputed from ids_lens>0

  float* out = (float*)d_out;  // [1 + B*S]: loss, then argmax as float

  float2* partials = (float2*)d_ws;  // 256 float2

  fused_kernel<<<Bdim * 4, 512, 0, stream>>>(enc, W, bias, attn, ids_lens,
                                             label_ids, out, partials);
  final_kernel<<<1, 256, 0, stream>>>(partials, out);
}